// Round 1
// baseline (677.908 us; speedup 1.0000x reference)
//
#include <hip/hip_runtime.h>
#include <math.h>

#define D 2
#define B 64
#define P 512
#define NV 64
#define H 64
#define TW 128
#define NQ (B*NV + B)   // 4160

// ---------------- Kernel A: coeff (attention) ----------------
// one block (256 threads) per query; each thread handles positions tid, tid+256
__global__ __launch_bounds__(256) void coeff_kernel(
    const float* __restrict__ coords, const float* __restrict__ vel,
    const float* __restrict__ pos, const float* __restrict__ sigma,
    const float* __restrict__ aW0, const float* __restrict__ ab0,
    const float* __restrict__ aW1, const float* __restrict__ ab1,
    const float* __restrict__ aW2, const float* __restrict__ ab2,
    float* __restrict__ coeff_out)
{
    __shared__ float s_aW0[6*H];
    __shared__ float s_ab0[H];
    __shared__ float s_aW1t[H*H];   // transposed: [k2][k]
    __shared__ float s_ab1[H];
    __shared__ float s_aW2[H];
    __shared__ float s_pos[P*2];
    __shared__ float s_sig[P];
    __shared__ float s_red[8];

    const int tid = threadIdx.x;
    for (int i = tid; i < 6*H; i += 256) s_aW0[i] = aW0[i];
    if (tid < H) { s_ab0[tid]=ab0[tid]; s_ab1[tid]=ab1[tid]; s_aW2[tid]=aW2[tid]; }
    for (int i = tid; i < H*H; i += 256) s_aW1t[(i & 63)*H + (i >> 6)] = aW1[i];
    for (int i = tid; i < P*2; i += 256) s_pos[i] = pos[i];
    for (int i = tid; i < P;   i += 256) s_sig[i] = sigma[i];
    __syncthreads();

    const int q = blockIdx.x;
    float x0, x1, v0, v1;
    {
        int b;
        if (q < B*NV) { b = q >> 6; const int j = q & 63;
            v0 = vel[2*j]; v1 = vel[2*j+1];
        } else { b = q - B*NV;
            v0 = coords[4*b+2]; v1 = coords[4*b+3];
        }
        x0 = coords[4*b]; x1 = coords[4*b+1];
    }
    const float rinv = rsqrtf(v0*v0 + v1*v1 + 1e-16f);
    const float a0 = v0*rinv, a1 = v1*rinv;
    const float bias2 = ab2[0];

    float logit[2];
    #pragma unroll
    for (int pp = 0; pp < 2; ++pp) {
        const int p = tid + 256*pp;
        const float rx = x0 - s_pos[2*p];
        const float ry = x1 - s_pos[2*p+1];
        const float rd = sqrtf(rx*rx + ry*ry + 1e-16f);
        const float pl = rx*a0 + ry*a1;
        const float al = pl / (rd + 1e-8f);

        float h1[H];
        #pragma unroll
        for (int k = 0; k < H; ++k) {
            float t = s_ab0[k]
                + x0*s_aW0[k]     + x1*s_aW0[H+k]
                + v0*s_aW0[2*H+k] + v1*s_aW0[3*H+k]
                + al*s_aW0[4*H+k] + pl*s_aW0[5*H+k];
            h1[k] = fmaxf(t, 0.f);
        }
        float lg = bias2;
        for (int k2 = 0; k2 < H; ++k2) {
            float acc = s_ab1[k2];
            const float* wr = &s_aW1t[k2*H];
            #pragma unroll
            for (int k = 0; k < H; k += 4) {
                const float4 w4 = *(const float4*)(wr + k);
                acc += h1[k]*w4.x + h1[k+1]*w4.y + h1[k+2]*w4.z + h1[k+3]*w4.w;
            }
            lg += fmaxf(acc, 0.f) * s_aW2[k2];
        }
        logit[pp] = (pl > 0.f) ? lg : -1e30f;
    }

    // masked softmax over 512 positions + weighted sigma sum
    float m = fmaxf(logit[0], logit[1]);
    #pragma unroll
    for (int o = 32; o > 0; o >>= 1) m = fmaxf(m, __shfl_down(m, o, 64));
    const int lane = tid & 63, wid = tid >> 6;
    if (lane == 0) s_red[wid] = m;
    __syncthreads();
    m = fmaxf(fmaxf(s_red[0], s_red[1]), fmaxf(s_red[2], s_red[3]));

    const float e0 = expf(logit[0] - m);
    const float e1 = expf(logit[1] - m);
    float s = e0 + e1;
    float t = e0*s_sig[tid] + e1*s_sig[tid+256];
    #pragma unroll
    for (int o = 32; o > 0; o >>= 1) { s += __shfl_down(s, o, 64); t += __shfl_down(t, o, 64); }
    __syncthreads();   // everyone done reading s_red (max phase)
    if (lane == 0) { s_red[wid] = s; s_red[4+wid] = t; }
    __syncthreads();
    if (tid == 0) {
        const float S = s_red[0]+s_red[1]+s_red[2]+s_red[3];
        const float T = s_red[4]+s_red[5]+s_red[6]+s_red[7];
        coeff_out[q] = expf(-(T/S));
    }
}

// ---------------- Kernel B: transport MLP ----------------
// one block (128 threads) per query; thread t owns output channel t
__global__ __launch_bounds__(128) void transport_kernel(
    const float* __restrict__ coords, const float* __restrict__ coordsp,
    const float* __restrict__ vel,
    const float* __restrict__ tW0, const float* __restrict__ tb0,
    const float* __restrict__ tW1, const float* __restrict__ tb1,
    const float* __restrict__ tW2, const float* __restrict__ tb2,
    const float* __restrict__ coeff_ws, float* __restrict__ cur_ws,
    float* __restrict__ g_ws)
{
    __shared__ float sh[TW];
    const int t = threadIdx.x, q = blockIdx.x;
    float in2, in3;
    int b;
    if (q < B*NV) { b = q >> 6; const int j = q & 63;
        in2 = vel[2*j]; in3 = vel[2*j+1];
    } else { b = q - B*NV;
        in2 = coords[4*b+2]; in3 = coords[4*b+3];
    }
    const float in0 = coords[4*b],  in1 = coords[4*b+1];
    const float p0 = coordsp[4*b],  p1 = coordsp[4*b+1];
    const float p2 = coordsp[4*b+2], p3 = coordsp[4*b+3];
    const float cf = coeff_ws[q];

    float h = tb0[t]
        + in0*tW0[t]       + in1*tW0[TW+t]   + in2*tW0[2*TW+t] + in3*tW0[3*TW+t]
        + p0 *tW0[4*TW+t]  + p1 *tW0[5*TW+t] + p2 *tW0[6*TW+t] + p3 *tW0[7*TW+t]
        + cf *tW0[8*TW+t];
    h = fmaxf(h, 0.f);
    sh[t] = h; __syncthreads();

    float h2 = tb1[t];
    for (int i = 0; i < TW; ++i) h2 += sh[i]*tW1[i*TW+t];
    h2 = fmaxf(h2, 0.f);
    __syncthreads(); sh[t] = h2; __syncthreads();

    float h3 = tb2[t];
    for (int i = 0; i < TW; ++i) h3 += sh[i]*tW2[i*TW+t];
    h3 = fmaxf(h3, 0.f);
    const float o = expf(h3);

    if (q < B*NV) cur_ws[q*TW + t] = o;
    else          g_ws[(q - B*NV)*TW + t] = o;
}

// ---------------- Kernel C: scattering recursion + output ----------------
// one block (128 threads) per batch row; thread w owns feature column w
__global__ __launch_bounds__(128) void scatter_kernel(
    const float* __restrict__ scat_k, const float* __restrict__ vw,
    const float* __restrict__ ssk,
    const float* __restrict__ rW, const float* __restrict__ rb,
    const float* __restrict__ fW, const float* __restrict__ fb,
    const float* __restrict__ cur_ws, const float* __restrict__ g_ws,
    float* __restrict__ out)
{
    __shared__ float s_rw[NV*NV];   // res_w[i][j]
    __shared__ float s_A[NV*TW];    // cur  (column-private per thread)
    __shared__ float s_Rt[NV*TW];   // r = res_w @ cur
    __shared__ float s_wl[NV];
    __shared__ float s_fin[2];

    const int w = threadIdx.x, b = blockIdx.x;
    for (int i = w; i < NV*NV; i += TW) s_rw[i] = (1.f - ssk[i]) * vw[i & 63];
    if (w < NV) s_wl[w] = (1.f - scat_k[b*NV + w]) * vw[w];
    for (int j = 0; j < NV; ++j) s_A[j*TW + w] = cur_ws[(b*NV + j)*TW + w];
    __syncthreads();

    float acc = 0.f;
    for (int j = 0; j < NV; ++j) acc += s_wl[j]*s_A[j*TW + w];   // outs[0]

    for (int l = 0; l < 2; ++l) {
        // r[i][w] = sum_j res_w[i][j] * cur[j][w]
        for (int i = 0; i < NV; ++i) {
            float r = 0.f;
            for (int j = 0; j < NV; ++j) r += s_rw[i*NV+j]*s_A[j*TW+w];
            s_Rt[i*TW+w] = r;
        }
        __syncthreads();
        const float* rWl = rW + l*TW*TW;
        const float rbv = rb[l*TW + w];
        for (int i = 0; i < NV; ++i) {
            float tt = rbv;
            for (int u = 0; u < TW; u += 4) {
                const float4 r4 = *(const float4*)&s_Rt[i*TW+u];
                tt += r4.x*rWl[u*TW+w]     + r4.y*rWl[(u+1)*TW+w]
                    + r4.z*rWl[(u+2)*TW+w] + r4.w*rWl[(u+3)*TW+w];
            }
            s_A[i*TW+w] += fmaxf(tt, 0.f);   // column-private write
        }
        __syncthreads();
        for (int j = 0; j < NV; ++j) acc += s_wl[j]*s_A[j*TW+w];  // outs[l+1]
    }

    const float gf = g_ws[b*TW + w] + acc;
    float part = gf * fW[w];
    #pragma unroll
    for (int o = 32; o > 0; o >>= 1) part += __shfl_down(part, o, 64);
    if ((w & 63) == 0) s_fin[w >> 6] = part;
    __syncthreads();
    if (w == 0) out[b] = s_fin[0] + s_fin[1] + fb[0];
}

extern "C" void kernel_launch(void* const* d_in, const int* in_sizes, int n_in,
                              void* d_out, int out_size, void* d_ws, size_t ws_size,
                              hipStream_t stream) {
    const float* coords  = (const float*)d_in[0];
    const float* coordsp = (const float*)d_in[1];
    const float* scatk   = (const float*)d_in[2];
    const float* pos     = (const float*)d_in[3];
    const float* sigma   = (const float*)d_in[4];
    const float* vel     = (const float*)d_in[5];
    const float* vw      = (const float*)d_in[6];
    const float* ssk     = (const float*)d_in[7];
    const float* aW0 = (const float*)d_in[8];
    const float* ab0 = (const float*)d_in[9];
    const float* aW1 = (const float*)d_in[10];
    const float* ab1 = (const float*)d_in[11];
    const float* aW2 = (const float*)d_in[12];
    const float* ab2 = (const float*)d_in[13];
    const float* tW0 = (const float*)d_in[14];
    const float* tb0 = (const float*)d_in[15];
    const float* tW1 = (const float*)d_in[16];
    const float* tb1 = (const float*)d_in[17];
    const float* tW2 = (const float*)d_in[18];
    const float* tb2 = (const float*)d_in[19];
    const float* rW  = (const float*)d_in[20];
    const float* rb  = (const float*)d_in[21];
    const float* fW  = (const float*)d_in[22];
    const float* fb  = (const float*)d_in[23];
    float* out = (float*)d_out;

    float* ws = (float*)d_ws;
    float* coeff_ws = ws;                    // NQ floats (4160), padded to 4224
    float* cur_ws   = ws + 4224;             // B*NV*TW floats
    float* g_ws     = cur_ws + B*NV*TW;      // B*TW floats

    hipLaunchKernelGGL(coeff_kernel, dim3(NQ), dim3(256), 0, stream,
        coords, vel, pos, sigma, aW0, ab0, aW1, ab1, aW2, ab2, coeff_ws);
    hipLaunchKernelGGL(transport_kernel, dim3(NQ), dim3(128), 0, stream,
        coords, coordsp, vel, tW0, tb0, tW1, tb1, tW2, tb2, coeff_ws, cur_ws, g_ws);
    hipLaunchKernelGGL(scatter_kernel, dim3(B), dim3(128), 0, stream,
        scatk, vw, ssk, rW, rb, fW, fb, cur_ws, g_ws, out);
}

// Round 2
// 353.004 us; speedup vs baseline: 1.9204x; 1.9204x over previous
//
#include <hip/hip_runtime.h>
#include <math.h>

#define D 2
#define B 64
#define P 512
#define NV 64
#define H 64
#define TW 128
#define NQ (B*NV + B)   // 4160

typedef short short8 __attribute__((ext_vector_type(8)));
typedef float f32x4 __attribute__((ext_vector_type(4)));

static __device__ __forceinline__ unsigned short f2bf(float f) {
    unsigned int u = __builtin_bit_cast(unsigned int, f);
    u += 0x7FFFu + ((u >> 16) & 1u);          // round-to-nearest-even
    return (unsigned short)(u >> 16);
}

// ---------------- Kernel A: coeff (attention) — MFMA layer2 ----------------
// one block (256 threads = 4 waves) per query; 4 chunks of 128 positions
__global__ __launch_bounds__(256) void coeff_kernel(
    const float* __restrict__ coords, const float* __restrict__ vel,
    const float* __restrict__ pos, const float* __restrict__ sigma,
    const float* __restrict__ aW0, const float* __restrict__ ab0,
    const float* __restrict__ aW1, const float* __restrict__ ab1,
    const float* __restrict__ aW2, const float* __restrict__ ab2,
    float* __restrict__ coeff_out)
{
    __shared__ unsigned short s_h1[128*72];    // h1 chunk, bf16, row stride 72 (pad: 2-way bank only)
    __shared__ unsigned short s_w1t[64*72];    // aW1 transposed [n][k], bf16, padded
    __shared__ float s_al[P], s_pl[P], s_sig[P], s_logit[P];
    __shared__ float s_base[H], s_w4[H], s_w5[H], s_aW2f[H], s_ab1f[H];
    __shared__ float s_red[8];

    const int tid  = threadIdx.x;
    const int lane = tid & 63, wid = tid >> 6;
    const int q = blockIdx.x;

    // ---- query scalars
    float x0, x1, v0, v1;
    {
        int b;
        if (q < B*NV) { b = q >> 6; const int j = q & 63;
            v0 = vel[2*j]; v1 = vel[2*j+1];
        } else { b = q - B*NV;
            v0 = coords[4*b+2]; v1 = coords[4*b+3];
        }
        x0 = coords[4*b]; x1 = coords[4*b+1];
    }
    const float rinv = rsqrtf(v0*v0 + v1*v1 + 1e-16f);
    const float a0 = v0*rinv, a1 = v1*rinv;

    // ---- stage aW1^T (bf16) : s_w1t[n][k] = aW1[k][n]
    for (int i = tid; i < H*H; i += 256) {
        const int k = i >> 6, n = i & 63;
        s_w1t[n*72 + k] = f2bf(aW1[i]);
    }
    // ---- layer1 collapsed coefficients (x,v terms are query-constant)
    if (tid < H) {
        const int k = tid;
        s_base[k] = ab0[k] + x0*aW0[k] + x1*aW0[64+k] + v0*aW0[128+k] + v1*aW0[192+k];
        s_w4[k]   = aW0[256+k];
        s_w5[k]   = aW0[320+k];
        s_aW2f[k] = aW2[k];
        s_ab1f[k] = ab1[k];
    }
    // ---- geometry: al, pl (fp32, exact for the mask), sigma
    #pragma unroll
    for (int pp = 0; pp < 2; ++pp) {
        const int p = tid + 256*pp;
        const float rx = x0 - pos[2*p];
        const float ry = x1 - pos[2*p+1];
        const float rd = sqrtf(rx*rx + ry*ry + 1e-16f);
        const float pl = rx*a0 + ry*a1;
        s_pl[p]  = pl;
        s_al[p]  = pl / (rd + 1e-8f);
        s_sig[p] = sigma[p];
    }
    __syncthreads();

    // ---- B fragments (aW1), kept in registers for all chunks
    // B layout for 16x16x32: col = lane&15, k = (lane>>4)*8 + j
    short8 bfrag[4][2];
    #pragma unroll
    for (int n = 0; n < 4; ++n)
        #pragma unroll
        for (int ks = 0; ks < 2; ++ks)
            bfrag[n][ks] = *(const short8*)&s_w1t[(n*16 + (lane & 15))*72 + ks*32 + (lane >> 4)*8];

    // ---- chunks of 128 positions
    for (int ch = 0; ch < 4; ++ch) {
        // layer1 -> s_h1 (bf16). thread: row tid>>1, cols (tid&1)*32 .. +31
        {
            const int r  = tid >> 1;
            const int c0 = (tid & 1) * 32;
            const int grow = ch*128 + r;
            const float al = s_al[grow], pl = s_pl[grow];
            unsigned short hv[32];
            #pragma unroll
            for (int c = 0; c < 32; ++c) {
                const int k = c0 + c;
                const float t = s_base[k] + al*s_w4[k] + pl*s_w5[k];
                hv[c] = f2bf(fmaxf(t, 0.f));
            }
            short8* dst = (short8*)&s_h1[r*72 + c0];
            #pragma unroll
            for (int j = 0; j < 4; ++j) {
                short8 v;
                #pragma unroll
                for (int e = 0; e < 8; ++e) v[e] = (short)hv[j*8 + e];
                dst[j] = v;
            }
        }
        __syncthreads();

        // layer2 MFMA + fused relu*aW2 epilogue. wave handles M-tiles {2*wid, 2*wid+1}
        #pragma unroll
        for (int mt = 0; mt < 2; ++mt) {
            const int mrow = (wid*2 + mt)*16 + (lane & 15);
            const short8 a0f = *(const short8*)&s_h1[mrow*72 +      (lane >> 4)*8];
            const short8 a1f = *(const short8*)&s_h1[mrow*72 + 32 + (lane >> 4)*8];
            float p0 = 0.f, p1 = 0.f, p2 = 0.f, p3 = 0.f;
            #pragma unroll
            for (int n = 0; n < 4; ++n) {
                f32x4 acc = {0.f, 0.f, 0.f, 0.f};
                acc = __builtin_amdgcn_mfma_f32_16x16x32_bf16(a0f, bfrag[n][0], acc, 0, 0, 0);
                acc = __builtin_amdgcn_mfma_f32_16x16x32_bf16(a1f, bfrag[n][1], acc, 0, 0, 0);
                const int col = n*16 + (lane & 15);
                const float w2 = s_aW2f[col];
                const float bb = s_ab1f[col];
                p0 += fmaxf(acc[0] + bb, 0.f) * w2;
                p1 += fmaxf(acc[1] + bb, 0.f) * w2;
                p2 += fmaxf(acc[2] + bb, 0.f) * w2;
                p3 += fmaxf(acc[3] + bb, 0.f) * w2;
            }
            // reduce over the 16 cols held by the 16-lane group
            #pragma unroll
            for (int off = 1; off < 16; off <<= 1) {
                p0 += __shfl_xor(p0, off, 64);
                p1 += __shfl_xor(p1, off, 64);
                p2 += __shfl_xor(p2, off, 64);
                p3 += __shfl_xor(p3, off, 64);
            }
            if ((lane & 15) == 0) {
                const int rb = ch*128 + (wid*2 + mt)*16 + (lane >> 4)*4;
                s_logit[rb]   = p0;
                s_logit[rb+1] = p1;
                s_logit[rb+2] = p2;
                s_logit[rb+3] = p3;
            }
        }
        __syncthreads();   // s_h1 reuse next chunk; also publishes s_logit
    }

    // ---- masked softmax + sigma dot.  NOTE: ab2 omitted (constant logit
    // shift on unmasked entries is softmax-invariant; masked stay -1e30).
    const float lg0 = (s_pl[tid]       > 0.f) ? s_logit[tid]       : -1e30f;
    const float lg1 = (s_pl[tid + 256] > 0.f) ? s_logit[tid + 256] : -1e30f;
    float m = fmaxf(lg0, lg1);
    #pragma unroll
    for (int o = 32; o > 0; o >>= 1) m = fmaxf(m, __shfl_down(m, o, 64));
    if (lane == 0) s_red[wid] = m;
    __syncthreads();
    m = fmaxf(fmaxf(s_red[0], s_red[1]), fmaxf(s_red[2], s_red[3]));

    const float e0 = expf(lg0 - m);
    const float e1 = expf(lg1 - m);
    float s = e0 + e1;
    float t = e0*s_sig[tid] + e1*s_sig[tid + 256];
    #pragma unroll
    for (int o = 32; o > 0; o >>= 1) { s += __shfl_down(s, o, 64); t += __shfl_down(t, o, 64); }
    __syncthreads();
    if (lane == 0) { s_red[wid] = s; s_red[4 + wid] = t; }
    __syncthreads();
    if (tid == 0) {
        const float S = s_red[0] + s_red[1] + s_red[2] + s_red[3];
        const float T = s_red[4] + s_red[5] + s_red[6] + s_red[7];
        coeff_out[q] = expf(-(T / S));
    }
}

// ---------------- Kernel B: transport MLP ----------------
__global__ __launch_bounds__(128) void transport_kernel(
    const float* __restrict__ coords, const float* __restrict__ coordsp,
    const float* __restrict__ vel,
    const float* __restrict__ tW0, const float* __restrict__ tb0,
    const float* __restrict__ tW1, const float* __restrict__ tb1,
    const float* __restrict__ tW2, const float* __restrict__ tb2,
    const float* __restrict__ coeff_ws, float* __restrict__ cur_ws,
    float* __restrict__ g_ws)
{
    __shared__ float sh[TW];
    const int t = threadIdx.x, q = blockIdx.x;
    float in2, in3;
    int b;
    if (q < B*NV) { b = q >> 6; const int j = q & 63;
        in2 = vel[2*j]; in3 = vel[2*j+1];
    } else { b = q - B*NV;
        in2 = coords[4*b+2]; in3 = coords[4*b+3];
    }
    const float in0 = coords[4*b],  in1 = coords[4*b+1];
    const float p0 = coordsp[4*b],  p1 = coordsp[4*b+1];
    const float p2 = coordsp[4*b+2], p3 = coordsp[4*b+3];
    const float cf = coeff_ws[q];

    float h = tb0[t]
        + in0*tW0[t]       + in1*tW0[TW+t]   + in2*tW0[2*TW+t] + in3*tW0[3*TW+t]
        + p0 *tW0[4*TW+t]  + p1 *tW0[5*TW+t] + p2 *tW0[6*TW+t] + p3 *tW0[7*TW+t]
        + cf *tW0[8*TW+t];
    h = fmaxf(h, 0.f);
    sh[t] = h; __syncthreads();

    float h2 = tb1[t];
    for (int i = 0; i < TW; ++i) h2 += sh[i]*tW1[i*TW+t];
    h2 = fmaxf(h2, 0.f);
    __syncthreads(); sh[t] = h2; __syncthreads();

    float h3 = tb2[t];
    for (int i = 0; i < TW; ++i) h3 += sh[i]*tW2[i*TW+t];
    h3 = fmaxf(h3, 0.f);
    const float o = expf(h3);

    if (q < B*NV) cur_ws[q*TW + t] = o;
    else          g_ws[(q - B*NV)*TW + t] = o;
}

// ---------------- Kernel C: scattering recursion + output ----------------
__global__ __launch_bounds__(128) void scatter_kernel(
    const float* __restrict__ scat_k, const float* __restrict__ vw,
    const float* __restrict__ ssk,
    const float* __restrict__ rW, const float* __restrict__ rb,
    const float* __restrict__ fW, const float* __restrict__ fb,
    const float* __restrict__ cur_ws, const float* __restrict__ g_ws,
    float* __restrict__ out)
{
    __shared__ float s_rw[NV*NV];
    __shared__ float s_A[NV*TW];
    __shared__ float s_Rt[NV*TW];
    __shared__ float s_wl[NV];
    __shared__ float s_fin[2];

    const int w = threadIdx.x, b = blockIdx.x;
    for (int i = w; i < NV*NV; i += TW) s_rw[i] = (1.f - ssk[i]) * vw[i & 63];
    if (w < NV) s_wl[w] = (1.f - scat_k[b*NV + w]) * vw[w];
    for (int j = 0; j < NV; ++j) s_A[j*TW + w] = cur_ws[(b*NV + j)*TW + w];
    __syncthreads();

    float acc = 0.f;
    for (int j = 0; j < NV; ++j) acc += s_wl[j]*s_A[j*TW + w];

    for (int l = 0; l < 2; ++l) {
        for (int i = 0; i < NV; ++i) {
            float r = 0.f;
            for (int j = 0; j < NV; ++j) r += s_rw[i*NV+j]*s_A[j*TW+w];
            s_Rt[i*TW+w] = r;
        }
        __syncthreads();
        const float* rWl = rW + l*TW*TW;
        const float rbv = rb[l*TW + w];
        for (int i = 0; i < NV; ++i) {
            float tt = rbv;
            for (int u = 0; u < TW; u += 4) {
                const float4 r4 = *(const float4*)&s_Rt[i*TW+u];
                tt += r4.x*rWl[u*TW+w]     + r4.y*rWl[(u+1)*TW+w]
                    + r4.z*rWl[(u+2)*TW+w] + r4.w*rWl[(u+3)*TW+w];
            }
            s_A[i*TW+w] += fmaxf(tt, 0.f);
        }
        __syncthreads();
        for (int j = 0; j < NV; ++j) acc += s_wl[j]*s_A[j*TW+w];
    }

    const float gf = g_ws[b*TW + w] + acc;
    float part = gf * fW[w];
    #pragma unroll
    for (int o = 32; o > 0; o >>= 1) part += __shfl_down(part, o, 64);
    if ((w & 63) == 0) s_fin[w >> 6] = part;
    __syncthreads();
    if (w == 0) out[b] = s_fin[0] + s_fin[1] + fb[0];
}

extern "C" void kernel_launch(void* const* d_in, const int* in_sizes, int n_in,
                              void* d_out, int out_size, void* d_ws, size_t ws_size,
                              hipStream_t stream) {
    const float* coords  = (const float*)d_in[0];
    const float* coordsp = (const float*)d_in[1];
    const float* scatk   = (const float*)d_in[2];
    const float* pos     = (const float*)d_in[3];
    const float* sigma   = (const float*)d_in[4];
    const float* vel     = (const float*)d_in[5];
    const float* vw      = (const float*)d_in[6];
    const float* ssk     = (const float*)d_in[7];
    const float* aW0 = (const float*)d_in[8];
    const float* ab0 = (const float*)d_in[9];
    const float* aW1 = (const float*)d_in[10];
    const float* ab1 = (const float*)d_in[11];
    const float* aW2 = (const float*)d_in[12];
    const float* ab2 = (const float*)d_in[13];
    const float* tW0 = (const float*)d_in[14];
    const float* tb0 = (const float*)d_in[15];
    const float* tW1 = (const float*)d_in[16];
    const float* tb1 = (const float*)d_in[17];
    const float* tW2 = (const float*)d_in[18];
    const float* tb2 = (const float*)d_in[19];
    const float* rW  = (const float*)d_in[20];
    const float* rb  = (const float*)d_in[21];
    const float* fW  = (const float*)d_in[22];
    const float* fb  = (const float*)d_in[23];
    float* out = (float*)d_out;

    float* ws = (float*)d_ws;
    float* coeff_ws = ws;                    // NQ floats, padded
    float* cur_ws   = ws + 4224;             // B*NV*TW floats
    float* g_ws     = cur_ws + B*NV*TW;      // B*TW floats

    hipLaunchKernelGGL(coeff_kernel, dim3(NQ), dim3(256), 0, stream,
        coords, vel, pos, sigma, aW0, ab0, aW1, ab1, aW2, ab2, coeff_ws);
    hipLaunchKernelGGL(transport_kernel, dim3(NQ), dim3(128), 0, stream,
        coords, coordsp, vel, tW0, tb0, tW1, tb1, tW2, tb2, coeff_ws, cur_ws, g_ws);
    hipLaunchKernelGGL(scatter_kernel, dim3(B), dim3(128), 0, stream,
        scatk, vw, ssk, rW, rb, fW, fb, cur_ws, g_ws, out);
}

// Round 3
// 105.746 us; speedup vs baseline: 6.4107x; 3.3382x over previous
//
#include <hip/hip_runtime.h>
#include <math.h>

#define D 2
#define B 64
#define P 512
#define NV 64
#define H 64
#define TW 128
#define NQ (B*NV + B)   // 4160

typedef short short8 __attribute__((ext_vector_type(8)));
typedef short short4v __attribute__((ext_vector_type(4)));
typedef float f32x4 __attribute__((ext_vector_type(4)));

static __device__ __forceinline__ unsigned short f2bf(float f) {
    unsigned int u = __builtin_bit_cast(unsigned int, f);
    u += 0x7FFFu + ((u >> 16) & 1u);          // round-to-nearest-even
    return (unsigned short)(u >> 16);
}

// ---------------- Kernel A: coeff (attention) — MFMA layer2 ----------------
// one block (256 threads = 4 waves) per query; 4 chunks of 128 positions
__global__ __launch_bounds__(256) void coeff_kernel(
    const float* __restrict__ coords, const float* __restrict__ vel,
    const float* __restrict__ pos, const float* __restrict__ sigma,
    const float* __restrict__ aW0, const float* __restrict__ ab0,
    const float* __restrict__ aW1, const float* __restrict__ ab1,
    const float* __restrict__ aW2, const float* __restrict__ ab2,
    float* __restrict__ coeff_out)
{
    __shared__ unsigned short s_h1[128*72];
    __shared__ unsigned short s_w1t[64*72];
    __shared__ float s_al[P], s_pl[P], s_sig[P], s_logit[P];
    __shared__ float s_base[H], s_w4[H], s_w5[H], s_aW2f[H], s_ab1f[H];
    __shared__ float s_red[8];

    const int tid  = threadIdx.x;
    const int lane = tid & 63, wid = tid >> 6;
    const int q = blockIdx.x;

    float x0, x1, v0, v1;
    {
        int b;
        if (q < B*NV) { b = q >> 6; const int j = q & 63;
            v0 = vel[2*j]; v1 = vel[2*j+1];
        } else { b = q - B*NV;
            v0 = coords[4*b+2]; v1 = coords[4*b+3];
        }
        x0 = coords[4*b]; x1 = coords[4*b+1];
    }
    const float rinv = rsqrtf(v0*v0 + v1*v1 + 1e-16f);
    const float a0 = v0*rinv, a1 = v1*rinv;

    for (int i = tid; i < H*H; i += 256) {
        const int k = i >> 6, n = i & 63;
        s_w1t[n*72 + k] = f2bf(aW1[i]);
    }
    if (tid < H) {
        const int k = tid;
        s_base[k] = ab0[k] + x0*aW0[k] + x1*aW0[64+k] + v0*aW0[128+k] + v1*aW0[192+k];
        s_w4[k]   = aW0[256+k];
        s_w5[k]   = aW0[320+k];
        s_aW2f[k] = aW2[k];
        s_ab1f[k] = ab1[k];
    }
    #pragma unroll
    for (int pp = 0; pp < 2; ++pp) {
        const int p = tid + 256*pp;
        const float rx = x0 - pos[2*p];
        const float ry = x1 - pos[2*p+1];
        const float rd = sqrtf(rx*rx + ry*ry + 1e-16f);
        const float pl = rx*a0 + ry*a1;
        s_pl[p]  = pl;
        s_al[p]  = pl / (rd + 1e-8f);
        s_sig[p] = sigma[p];
    }
    __syncthreads();

    short8 bfrag[4][2];
    #pragma unroll
    for (int n = 0; n < 4; ++n)
        #pragma unroll
        for (int ks = 0; ks < 2; ++ks)
            bfrag[n][ks] = *(const short8*)&s_w1t[(n*16 + (lane & 15))*72 + ks*32 + (lane >> 4)*8];

    for (int ch = 0; ch < 4; ++ch) {
        {
            const int r  = tid >> 1;
            const int c0 = (tid & 1) * 32;
            const int grow = ch*128 + r;
            const float al = s_al[grow], pl = s_pl[grow];
            unsigned short hv[32];
            #pragma unroll
            for (int c = 0; c < 32; ++c) {
                const int k = c0 + c;
                const float t = s_base[k] + al*s_w4[k] + pl*s_w5[k];
                hv[c] = f2bf(fmaxf(t, 0.f));
            }
            short8* dst = (short8*)&s_h1[r*72 + c0];
            #pragma unroll
            for (int j = 0; j < 4; ++j) {
                short8 v;
                #pragma unroll
                for (int e = 0; e < 8; ++e) v[e] = (short)hv[j*8 + e];
                dst[j] = v;
            }
        }
        __syncthreads();

        #pragma unroll
        for (int mt = 0; mt < 2; ++mt) {
            const int mrow = (wid*2 + mt)*16 + (lane & 15);
            const short8 a0f = *(const short8*)&s_h1[mrow*72 +      (lane >> 4)*8];
            const short8 a1f = *(const short8*)&s_h1[mrow*72 + 32 + (lane >> 4)*8];
            float p0 = 0.f, p1 = 0.f, p2 = 0.f, p3 = 0.f;
            #pragma unroll
            for (int n = 0; n < 4; ++n) {
                f32x4 acc = {0.f, 0.f, 0.f, 0.f};
                acc = __builtin_amdgcn_mfma_f32_16x16x32_bf16(a0f, bfrag[n][0], acc, 0, 0, 0);
                acc = __builtin_amdgcn_mfma_f32_16x16x32_bf16(a1f, bfrag[n][1], acc, 0, 0, 0);
                const int col = n*16 + (lane & 15);
                const float w2 = s_aW2f[col];
                const float bb = s_ab1f[col];
                p0 += fmaxf(acc[0] + bb, 0.f) * w2;
                p1 += fmaxf(acc[1] + bb, 0.f) * w2;
                p2 += fmaxf(acc[2] + bb, 0.f) * w2;
                p3 += fmaxf(acc[3] + bb, 0.f) * w2;
            }
            #pragma unroll
            for (int off = 1; off < 16; off <<= 1) {
                p0 += __shfl_xor(p0, off, 64);
                p1 += __shfl_xor(p1, off, 64);
                p2 += __shfl_xor(p2, off, 64);
                p3 += __shfl_xor(p3, off, 64);
            }
            if ((lane & 15) == 0) {
                const int rb = ch*128 + (wid*2 + mt)*16 + (lane >> 4)*4;
                s_logit[rb]   = p0;
                s_logit[rb+1] = p1;
                s_logit[rb+2] = p2;
                s_logit[rb+3] = p3;
            }
        }
        __syncthreads();
    }

    const float lg0 = (s_pl[tid]       > 0.f) ? s_logit[tid]       : -1e30f;
    const float lg1 = (s_pl[tid + 256] > 0.f) ? s_logit[tid + 256] : -1e30f;
    float m = fmaxf(lg0, lg1);
    #pragma unroll
    for (int o = 32; o > 0; o >>= 1) m = fmaxf(m, __shfl_down(m, o, 64));
    if (lane == 0) s_red[wid] = m;
    __syncthreads();
    m = fmaxf(fmaxf(s_red[0], s_red[1]), fmaxf(s_red[2], s_red[3]));

    const float e0 = expf(lg0 - m);
    const float e1 = expf(lg1 - m);
    float s = e0 + e1;
    float t = e0*s_sig[tid] + e1*s_sig[tid + 256];
    #pragma unroll
    for (int o = 32; o > 0; o >>= 1) { s += __shfl_down(s, o, 64); t += __shfl_down(t, o, 64); }
    __syncthreads();
    if (lane == 0) { s_red[wid] = s; s_red[4 + wid] = t; }
    __syncthreads();
    if (tid == 0) {
        const float S = s_red[0] + s_red[1] + s_red[2] + s_red[3];
        const float T = s_red[4] + s_red[5] + s_red[6] + s_red[7];
        coeff_out[q] = expf(-(T / S));
    }
}

// ---------------- Kernel B: transport MLP ----------------
__global__ __launch_bounds__(128) void transport_kernel(
    const float* __restrict__ coords, const float* __restrict__ coordsp,
    const float* __restrict__ vel,
    const float* __restrict__ tW0, const float* __restrict__ tb0,
    const float* __restrict__ tW1, const float* __restrict__ tb1,
    const float* __restrict__ tW2, const float* __restrict__ tb2,
    const float* __restrict__ coeff_ws, float* __restrict__ cur_ws,
    float* __restrict__ g_ws)
{
    __shared__ float sh[TW];
    const int t = threadIdx.x, q = blockIdx.x;
    float in2, in3;
    int b;
    if (q < B*NV) { b = q >> 6; const int j = q & 63;
        in2 = vel[2*j]; in3 = vel[2*j+1];
    } else { b = q - B*NV;
        in2 = coords[4*b+2]; in3 = coords[4*b+3];
    }
    const float in0 = coords[4*b],  in1 = coords[4*b+1];
    const float p0 = coordsp[4*b],  p1 = coordsp[4*b+1];
    const float p2 = coordsp[4*b+2], p3 = coordsp[4*b+3];
    const float cf = coeff_ws[q];

    float h = tb0[t]
        + in0*tW0[t]       + in1*tW0[TW+t]   + in2*tW0[2*TW+t] + in3*tW0[3*TW+t]
        + p0 *tW0[4*TW+t]  + p1 *tW0[5*TW+t] + p2 *tW0[6*TW+t] + p3 *tW0[7*TW+t]
        + cf *tW0[8*TW+t];
    h = fmaxf(h, 0.f);
    sh[t] = h; __syncthreads();

    float h2 = tb1[t];
    for (int i = 0; i < TW; ++i) h2 += sh[i]*tW1[i*TW+t];
    h2 = fmaxf(h2, 0.f);
    __syncthreads(); sh[t] = h2; __syncthreads();

    float h3 = tb2[t];
    for (int i = 0; i < TW; ++i) h3 += sh[i]*tW2[i*TW+t];
    h3 = fmaxf(h3, 0.f);
    const float o = expf(h3);

    if (q < B*NV) cur_ws[q*TW + t] = o;
    else          g_ws[(q - B*NV)*TW + t] = o;
}

// ---------------- Kernel C: scattering recursion + output (MFMA) ----------------
// one block per batch row b; 512 threads = 8 waves in a 4(M) x 2(N) wave grid.
// A (64x128) and S = A0+A1+A2 live in fp32 registers at MFMA C-layout positions.
__global__ __launch_bounds__(512) void scatter_kernel(
    const float* __restrict__ scat_k, const float* __restrict__ vw,
    const float* __restrict__ ssk,
    const float* __restrict__ rW, const float* __restrict__ rb,
    const float* __restrict__ fW, const float* __restrict__ fb,
    const float* __restrict__ cur_ws, const float* __restrict__ g_ws,
    float* __restrict__ out)
{
    __shared__ unsigned short s_At[128*72];    // A^T  [w][j], bf16, stride 72
    __shared__ unsigned short s_r[64*136];     // r    [i][u], bf16, stride 136
    __shared__ unsigned short s_rWt[128*136];  // rW^T [w2][u], bf16, stride 136
    __shared__ float s_wl[NV];
    __shared__ float s_fin[4*128];
    __shared__ float s_red[2];

    const int tid = threadIdx.x, b = blockIdx.x;
    const int lane = tid & 63, wid = tid >> 6;
    const int wm = wid & 3, wn = wid >> 2;      // wave tile: rows wm*16.., cols wn*64..
    const int l15 = lane & 15, lg = lane >> 4;
    const int irow = wm*16 + lg*4;              // C-layout row base for this lane

    if (tid < NV) s_wl[tid] = (1.f - scat_k[b*NV + tid]) * vw[tid];

    // stage A0^T (bf16)
    {
        const int w = tid & 127, j0 = tid >> 7;
        #pragma unroll
        for (int k = 0; k < 16; ++k) {
            const int j = j0 + 4*k;
            s_At[w*72 + j] = f2bf(cur_ws[(b*NV + j)*TW + w]);
        }
    }

    // fp32 register copies of A and S at C-layout positions
    float areg[4][4], sreg[4][4];
    #pragma unroll
    for (int n = 0; n < 4; ++n) {
        const int wcol = wn*64 + n*16 + l15;
        #pragma unroll
        for (int rg = 0; rg < 4; ++rg) {
            const float v = cur_ws[(b*NV + irow + rg)*TW + wcol];
            areg[n][rg] = v; sreg[n][rg] = v;
        }
    }

    for (int l = 0; l < 2; ++l) {
        // stage rW[l]^T (bf16)
        {
            const float* rWl = rW + l*TW*TW;
            const int w = tid & 127, u0 = (tid >> 7)*4;
            #pragma unroll
            for (int k = 0; k < 8; ++k) {
                const int u = u0 + 16*k;
                short4v pk;
                #pragma unroll
                for (int c = 0; c < 4; ++c) pk[c] = (short)f2bf(rWl[(u+c)*TW + w]);
                *(short4v*)&s_rWt[w*136 + u] = pk;
            }
        }
        __syncthreads();

        // GEMM1: r = res_w @ A   (M64, N128, K64), res_w from global on the fly
        {
            short8 afrag[2];
            const int row = wm*16 + l15;
            #pragma unroll
            for (int ks = 0; ks < 2; ++ks) {
                const int k0 = ks*32 + lg*8;
                #pragma unroll
                for (int j = 0; j < 8; ++j) {
                    const float rv = (1.f - ssk[row*NV + k0 + j]) * vw[k0 + j];
                    afrag[ks][j] = (short)f2bf(rv);
                }
            }
            #pragma unroll
            for (int n = 0; n < 4; ++n) {
                const int col = wn*64 + n*16 + l15;
                f32x4 acc = {0.f, 0.f, 0.f, 0.f};
                #pragma unroll
                for (int ks = 0; ks < 2; ++ks) {
                    const short8 bfr = *(const short8*)&s_At[col*72 + ks*32 + lg*8];
                    acc = __builtin_amdgcn_mfma_f32_16x16x32_bf16(afrag[ks], bfr, acc, 0, 0, 0);
                }
                #pragma unroll
                for (int rg = 0; rg < 4; ++rg)
                    s_r[(irow + rg)*136 + col] = f2bf(acc[rg]);
            }
        }
        __syncthreads();

        // GEMM2: T = r @ rW[l]  (M64, N128, K128); A += relu(T + rb); S += A
        {
            short8 af2[4];
            #pragma unroll
            for (int ks = 0; ks < 4; ++ks)
                af2[ks] = *(const short8*)&s_r[(wm*16 + l15)*136 + ks*32 + lg*8];
            #pragma unroll
            for (int n = 0; n < 4; ++n) {
                const int col = wn*64 + n*16 + l15;
                f32x4 acc = {0.f, 0.f, 0.f, 0.f};
                #pragma unroll
                for (int ks = 0; ks < 4; ++ks) {
                    const short8 bfr = *(const short8*)&s_rWt[col*136 + ks*32 + lg*8];
                    acc = __builtin_amdgcn_mfma_f32_16x16x32_bf16(af2[ks], bfr, acc, 0, 0, 0);
                }
                const float rbv = rb[l*TW + col];
                short4v pk;
                #pragma unroll
                for (int rg = 0; rg < 4; ++rg) {
                    areg[n][rg] += fmaxf(acc[rg] + rbv, 0.f);
                    sreg[n][rg] += areg[n][rg];
                    pk[rg] = (short)f2bf(areg[n][rg]);
                }
                *(short4v*)&s_At[col*72 + irow] = pk;   // A_new^T for next layer
            }
        }
        __syncthreads();
    }

    // output: part[w] = sum_i wl[i]*S[i][w]
    float p[4];
    #pragma unroll
    for (int n = 0; n < 4; ++n) {
        float acc = 0.f;
        #pragma unroll
        for (int rg = 0; rg < 4; ++rg) acc += s_wl[irow + rg] * sreg[n][rg];
        acc += __shfl_xor(acc, 16, 64);
        acc += __shfl_xor(acc, 32, 64);
        p[n] = acc;
    }
    if (lg == 0) {
        #pragma unroll
        for (int n = 0; n < 4; ++n)
            s_fin[wm*128 + wn*64 + n*16 + l15] = p[n];
    }
    __syncthreads();

    if (tid < 128) {
        const int w = tid;
        const float tot = s_fin[w] + s_fin[128 + w] + s_fin[256 + w] + s_fin[384 + w];
        float pw = (g_ws[b*TW + w] + tot) * fW[w];
        #pragma unroll
        for (int o = 32; o > 0; o >>= 1) pw += __shfl_down(pw, o, 64);
        if ((tid & 63) == 0) s_red[tid >> 6] = pw;
    }
    __syncthreads();
    if (tid == 0) out[b] = s_red[0] + s_red[1] + fb[0];
}

extern "C" void kernel_launch(void* const* d_in, const int* in_sizes, int n_in,
                              void* d_out, int out_size, void* d_ws, size_t ws_size,
                              hipStream_t stream) {
    const float* coords  = (const float*)d_in[0];
    const float* coordsp = (const float*)d_in[1];
    const float* scatk   = (const float*)d_in[2];
    const float* pos     = (const float*)d_in[3];
    const float* sigma   = (const float*)d_in[4];
    const float* vel     = (const float*)d_in[5];
    const float* vw      = (const float*)d_in[6];
    const float* ssk     = (const float*)d_in[7];
    const float* aW0 = (const float*)d_in[8];
    const float* ab0 = (const float*)d_in[9];
    const float* aW1 = (const float*)d_in[10];
    const float* ab1 = (const float*)d_in[11];
    const float* aW2 = (const float*)d_in[12];
    const float* ab2 = (const float*)d_in[13];
    const float* tW0 = (const float*)d_in[14];
    const float* tb0 = (const float*)d_in[15];
    const float* tW1 = (const float*)d_in[16];
    const float* tb1 = (const float*)d_in[17];
    const float* tW2 = (const float*)d_in[18];
    const float* tb2 = (const float*)d_in[19];
    const float* rW  = (const float*)d_in[20];
    const float* rb  = (const float*)d_in[21];
    const float* fW  = (const float*)d_in[22];
    const float* fb  = (const float*)d_in[23];
    float* out = (float*)d_out;

    float* ws = (float*)d_ws;
    float* coeff_ws = ws;                    // NQ floats, padded
    float* cur_ws   = ws + 4224;             // B*NV*TW floats
    float* g_ws     = cur_ws + B*NV*TW;      // B*TW floats

    hipLaunchKernelGGL(coeff_kernel, dim3(NQ), dim3(256), 0, stream,
        coords, vel, pos, sigma, aW0, ab0, aW1, ab1, aW2, ab2, coeff_ws);
    hipLaunchKernelGGL(transport_kernel, dim3(NQ), dim3(128), 0, stream,
        coords, coordsp, vel, tW0, tb0, tW1, tb1, tW2, tb2, coeff_ws, cur_ws, g_ws);
    hipLaunchKernelGGL(scatter_kernel, dim3(B), dim3(512), 0, stream,
        scatk, vw, ssk, rW, rb, fW, fb, cur_ws, g_ws, out);
}